// Round 14
// baseline (180.826 us; speedup 1.0000x reference)
//
#include <hip/hip_runtime.h>

#define NN 16384   // total nodes (4*64*64)
#define CC 48      // channels

typedef __attribute__((ext_vector_type(8))) short bf16x8;
typedef __attribute__((ext_vector_type(4))) float f32x4;

__device__ __forceinline__ unsigned short f2bf(float f) {
  unsigned u = __float_as_uint(f);
  unsigned r = ((u >> 16) & 1u) + 0x7fffu;   // RNE
  return (unsigned short)((u + r) >> 16);
}
__device__ __forceinline__ float bf2f(unsigned short h) {
  return __uint_as_float(((unsigned)h) << 16);
}

// Parallel sorted-insert of key c into ascending q[0..8] (verified R0 form).
// Queue datatype frozen (8 variants lost). R11/R12: the lever is concurrent
// independent chains per SIMD. R14 retries R13's 8-chains/SIMD config with
// LDS cut 147KB -> 73.7KB (R13's launch silently failed: absmax 6.64 ==
// "prep+out ran, knn didn't" fingerprint; 147KB exceeded the per-WG limit,
// proven ceiling here is <=128KB).
__device__ __forceinline__ void ins9(double c, double q[9]) {
  double m1 = fmin(q[1], c), m2 = fmin(q[2], c), m3 = fmin(q[3], c),
         m4 = fmin(q[4], c), m5 = fmin(q[5], c), m6 = fmin(q[6], c),
         m7 = fmin(q[7], c), m8 = fmin(q[8], c);
  double n0 = fmin(q[0], c);
  double n1 = fmax(q[0], m1), n2 = fmax(q[1], m2), n3 = fmax(q[2], m3),
         n4 = fmax(q[3], m4), n5 = fmax(q[4], m5), n6 = fmax(q[5], m6),
         n7 = fmax(q[6], m7), n8 = fmax(q[7], m8);
  q[0] = n0; q[1] = n1; q[2] = n2; q[3] = n3; q[4] = n4;
  q[5] = n5; q[6] = n6; q[7] = n7; q[8] = n8;
}

// 9-way u64 sorted-merge insert used by the staging merges (verified form).
__device__ __forceinline__ void mrg9(const unsigned long long* ob,
                                     unsigned long long q9u[9]) {
  for (int k = 0; k < 9; ++k) {
    unsigned long long key = ob[k];
    if (key >= q9u[8]) break;          // source sorted ascending
    unsigned long long cu = key;
#pragma unroll
    for (int kk = 0; kk < 9; ++kk) {
      bool lt = cu < q9u[kk];
      unsigned long long mn = lt ? cu : q9u[kk];
      cu      = lt ? q9u[kk] : cu;
      q9u[kk] = mn;
    }
  }
}

// ---------- kernel 1: prep, 1024 blocks x 16-node slice (verified R10) ----------
__global__ __launch_bounds__(256) void prep_kernel(const float* __restrict__ x,
                                                   float* __restrict__ xg,
                                                   unsigned short* __restrict__ xh,
                                                   unsigned short* __restrict__ xl,
                                                   float* __restrict__ sqv,
                                                   int* __restrict__ deg) {
  __shared__ __align__(16) float tile[48][20];   // 16 cols + pad to 20 (80B rows)
  __shared__ float sqcol[16];
  int tid = threadIdx.x;
  int n0    = blockIdx.x * 16;          // first node of this slice
  int batch = n0 >> 12;
  int hw0   = n0 & 4095;                // 16-aligned within the image
  if (tid < 16) deg[n0 + tid] = 0;
  const float4* x4 = (const float4*)x;
  if (tid < 192) {                      // 48 rows x 4 float4 (16 cols)
    int r = tid >> 2, c4 = tid & 3;
    float4 v = x4[(batch * 48 + r) * 1024 + (hw0 >> 2) + c4];
    *(float4*)&tile[r][c4 * 4] = v;
  }
  __syncthreads();
  if (tid < 16) {
    float s = 0.f;
#pragma unroll
    for (int r = 0; r < 48; ++r) { float v = tile[r][tid]; s += v * v; }
    sqcol[tid] = s;
    int node = n0 + tid;
    sqv[node] = (node == NN - 1) ? __builtin_inff() : s;
  }
  __syncthreads();
  float4* xg4 = (float4*)xg;
  if (tid < 208) {                      // 16 nodes x 13 float4
    int col = tid / 13, q = tid - col * 13;
    float4 v;
    if (q < 12) {
      v.x = tile[q * 4 + 0][col]; v.y = tile[q * 4 + 1][col];
      v.z = tile[q * 4 + 2][col]; v.w = tile[q * 4 + 3][col];
    } else {
      v.x = sqcol[col]; v.y = 0.f; v.z = 0.f; v.w = 0.f;
    }
    xg4[(n0 + col) * 13 + q] = v;
  }
  {                                     // 16 nodes x 16 ch-quads = 256 threads
    int col = tid >> 4, cq = tid & 15, ch = cq * 4;
    ushort4 h4, l4;
    if (ch < 48) {
      float v0 = tile[ch + 0][col], v1 = tile[ch + 1][col],
            v2 = tile[ch + 2][col], v3 = tile[ch + 3][col];
      h4.x = f2bf(v0); h4.y = f2bf(v1); h4.z = f2bf(v2); h4.w = f2bf(v3);
      l4.x = f2bf(v0 - bf2f(h4.x)); l4.y = f2bf(v1 - bf2f(h4.y));
      l4.z = f2bf(v2 - bf2f(h4.z)); l4.w = f2bf(v3 - bf2f(h4.w));
    } else {
      h4.x = h4.y = h4.z = h4.w = 0;
      l4.x = l4.y = l4.z = l4.w = 0;
    }
    size_t o = (size_t)(n0 + col) * 64 + ch;
    *(ushort4*)(xh + o) = h4;
    *(ushort4*)(xl + o) = l4;
  }
}

// ---------- kernel 2: QUAD-QUERY x 8-WAVE MFMA distance + exact f64 top-9 ----------
// R14 = R13 (quad-query body, 8 waves x 32-tile streams, 2 waves/SIMD) with
// merge staging restructured to fit the proven LDS budget:
//   scratch[8][64][9] (36.9KB): per-wave quad-merge staging, reused
//     sequentially for q=0..3 (wave-private region; in-wave LDS ops are
//     in-order, so reuse without cross-wave sync is safe — same assumption
//     as the verified R6-R12 pattern).
//   fmg[4][8][16][9] (36.9KB): only the lanes<16 merged per-wave lists that
//     stage 2 reads. Total 73,728 B == R12's proven size.
// Candidate re-partition (8 x 512-chunks) is order-transparent: merges
// compare packed (k32<<14)|j u64 (global (dist,j) order); per-query
// semantics byte-equivalent to frozen R6. Stage 2: waves 0-3 finalize
// queries 0-3 by merging all 8 wave-lists.
__global__ __launch_bounds__(512, 2) void knn_kernel(const unsigned short* __restrict__ xh,
                                                     const unsigned short* __restrict__ xl,
                                                     const float* __restrict__ sqv,
                                                     int* __restrict__ nbr,
                                                     int* __restrict__ deg) {
  __shared__ unsigned long long scratch[8][64][9];   // 36,864 B
  __shared__ unsigned long long fmg[4][8][16][9];    // 36,864 B
  int tid = threadIdx.x, wv = tid >> 6, lane = tid & 63;
  int qt0 = blockIdx.x * 4;
  int col = lane & 15, quad = lane >> 4;
  int batch = qt0 >> 8;
  int cbase = batch * 4096 + wv * 512;   // this wave's candidate eighth

  // resident B-frags: 4 query tiles (static indexing via full unroll)
  bf16x8 bh0[4], bh1[4], bl0[4], bl1[4];
#pragma unroll
  for (int q = 0; q < 4; ++q) {
    int qn = (qt0 + q) * 16 + col;
    bh0[q] = *(const bf16x8*)(xh + (size_t)qn * 64 + quad * 8);
    bh1[q] = *(const bf16x8*)(xh + (size_t)qn * 64 + 32 + quad * 8);
    bl0[q] = *(const bf16x8*)(xl + (size_t)qn * 64 + quad * 8);
    bl1[q] = *(const bf16x8*)(xl + (size_t)qn * 64 + 32 + quad * 8);
  }

  double q9[4][9];
#pragma unroll
  for (int q = 0; q < 4; ++q)
#pragma unroll
    for (int k = 0; k < 9; ++k) q9[q][k] = __builtin_inf();

  // prefetch tile 0: shared A-frags (candidate node cbase + col) + sq float4
  const unsigned short* pah = xh + ((size_t)(cbase + col) * 64 + quad * 8);
  const unsigned short* pal = xl + ((size_t)(cbase + col) * 64 + quad * 8);
  const float*          psq = sqv + (cbase + quad * 4);
  bf16x8 nh0 = *(const bf16x8*)(pah);
  bf16x8 nh1 = *(const bf16x8*)(pah + 32);
  bf16x8 nl0 = *(const bf16x8*)(pal);
  bf16x8 nl1 = *(const bf16x8*)(pal + 32);
  float4 nsq = *(const float4*)(psq);

  double od = 0.0;   // ordinal base = t*4 (exact integer in f64), shared
  for (int t = 0; t < 32; ++t) {
    bf16x8 ch0 = nh0, ch1 = nh1, cl0 = nl0, cl1 = nl1;
    float4 csq = nsq;
    int adv = (t < 31) ? 1024 : 0;       // 16 nodes * 64 ch
    pah += adv; pal += adv;
    nh0 = *(const bf16x8*)(pah);
    nh1 = *(const bf16x8*)(pah + 32);
    nl0 = *(const bf16x8*)(pal);
    nl1 = *(const bf16x8*)(pal + 32);
    psq += (t < 31) ? 16 : 0;
    nsq = *(const float4*)(psq);

    f32x4 acc[4];
#pragma unroll
    for (int q = 0; q < 4; ++q) acc[q] = (f32x4){0.f, 0.f, 0.f, 0.f};
#pragma unroll
    for (int q = 0; q < 4; ++q)
      acc[q] = __builtin_amdgcn_mfma_f32_16x16x32_bf16(ch0, bh0[q], acc[q], 0, 0, 0);
#pragma unroll
    for (int q = 0; q < 4; ++q)
      acc[q] = __builtin_amdgcn_mfma_f32_16x16x32_bf16(ch1, bh1[q], acc[q], 0, 0, 0);
#pragma unroll
    for (int q = 0; q < 4; ++q)
      acc[q] = __builtin_amdgcn_mfma_f32_16x16x32_bf16(ch0, bl0[q], acc[q], 0, 0, 0);
#pragma unroll
    for (int q = 0; q < 4; ++q)
      acc[q] = __builtin_amdgcn_mfma_f32_16x16x32_bf16(ch1, bl1[q], acc[q], 0, 0, 0);
#pragma unroll
    for (int q = 0; q < 4; ++q)
      acc[q] = __builtin_amdgcn_mfma_f32_16x16x32_bf16(cl0, bh0[q], acc[q], 0, 0, 0);
#pragma unroll
    for (int q = 0; q < 4; ++q)
      acc[q] = __builtin_amdgcn_mfma_f32_16x16x32_bf16(cl1, bh1[q], acc[q], 0, 0, 0);

    float sq4[4] = {csq.x, csq.y, csq.z, csq.w};
#pragma unroll
    for (int reg = 0; reg < 4; ++reg) {
      double ob = od + (double)reg;
#pragma unroll
      for (int q = 0; q < 4; ++q) {       // 4 independent insert chains
        float d = fmaf(-2.f, acc[q][reg], sq4[reg]);
        unsigned k32 = __float_as_uint(d);
        k32 = ((int)k32 >= 0) ? (k32 | 0x80000000u) : ~k32;   // sortable map
        double key = fma((double)k32, 256.0, ob);   // exact 40-bit int
        ins9(key, q9[q]);
      }
    }
    od += 4.0;
  }

  // stage 1 (per query, wave-private scratch): decode -> quad-merge -> fmg
#pragma unroll
  for (int q = 0; q < 4; ++q) {
#pragma unroll
    for (int k = 0; k < 9; ++k) {
      double d  = q9[q][k];
      double hi = floor(d * 0.00390625);     // d * 2^-8, exact
      double lo = d - hi * 256.0;            // ordinal o, exact
      unsigned k32 = (unsigned)hi;
      int o = (int)lo;
      int j = cbase + (o >> 2) * 16 + quad * 4 + (o & 3);
      scratch[wv][lane][k] = ((unsigned long long)k32 << 14) | (unsigned)j;
    }
    __threadfence_block();
    if (lane < 16) {
      unsigned long long qu[9];
#pragma unroll
      for (int k = 0; k < 9; ++k) qu[k] = scratch[wv][lane][k];
#pragma unroll
      for (int qd = 1; qd < 4; ++qd) mrg9(scratch[wv][qd * 16 + lane], qu);
#pragma unroll
      for (int k = 0; k < 9; ++k) fmg[q][wv][lane][k] = qu[k];
    }
    __threadfence_block();   // scratch reads done before next q's overwrite
  }
  __syncthreads();
  // stage 2: waves 0-3 finalize queries 0-3 (parallel); write nbr/deg
  if (wv < 4 && lane < 16) {
    unsigned long long qu[9];
#pragma unroll
    for (int k = 0; k < 9; ++k) qu[k] = fmg[wv][0][lane][k];
#pragma unroll
    for (int ow = 1; ow < 8; ++ow) mrg9(fmg[wv][ow][lane], qu);
    int i = (qt0 + wv) * 16 + lane;
    int outi[9];
#pragma unroll
    for (int k = 0; k < 9; ++k) outi[k] = (int)(qu[k] & 0x3FFFull);
    // node 16383 sits alone in "batch 4": neighbors {16383, 0..7}
    if (i == NN - 1) {
      outi[0] = NN - 1;
#pragma unroll
      for (int k = 1; k < 9; ++k) outi[k] = k - 1;
    }
#pragma unroll
    for (int k = 0; k < 9; ++k) {
      nbr[i * 9 + k] = outi[k];
      atomicAdd(&deg[outi[k]], 1);
    }
  }
}

// ---------- kernel 3: tx1 gather + out = relu(xf@W0 + tx1@W1 + b) ----------
// Verified R7/R10 version (1024 blocks x 16 rows). Unchanged.
__global__ __launch_bounds__(256) void out_kernel(const float* __restrict__ xg,
                                                  const int* __restrict__ nbr,
                                                  const int* __restrict__ deg,
                                                  const float* __restrict__ W0,
                                                  const float* __restrict__ W1,
                                                  const float* __restrict__ bias,
                                                  float* __restrict__ out) {
  __shared__ float w0s[48 * 48], w1s[48 * 48], bsh[48];
  __shared__ __align__(16) float xr[16 * 48];
  __shared__ float tx[16 * 48];
  __shared__ float wd[16][9];
  __shared__ int   jn[16][9];
  __shared__ float din[16];
  int tid = threadIdx.x;
  int r0  = blockIdx.x * 16;

  const float4* W04 = (const float4*)W0;
  const float4* W14 = (const float4*)W1;
  float4* w0s4 = (float4*)w0s;
  float4* w1s4 = (float4*)w1s;
  for (int p = tid; p < 576; p += 256) { w0s4[p] = W04[p]; w1s4[p] = W14[p]; }
  if (tid < 48) bsh[tid] = bias[tid];
  if (tid < 16) {
    int d = deg[r0 + tid];
    din[tid] = d > 0 ? rsqrtf((float)d) : 0.0f;
  }
  const float4* xg4 = (const float4*)xg;
  float4* xr4 = (float4*)xr;
  if (tid < 192) {                      // 16 rows x 12 float4
    int r = tid / 12, q = tid - r * 12;
    xr4[r * 12 + q] = xg4[(r0 + r) * 13 + q];
  }
  if (tid < 144) {                      // 16 rows x 9 neighbors
    int r = tid / 9, k = tid - r * 9;
    int j = nbr[(r0 + r) * 9 + k];
    jn[r][k] = j;
    int d = deg[j];
    wd[r][k] = d > 0 ? rsqrtf((float)d) : 0.0f;
  }
  __syncthreads();

  for (int p = tid; p < 768; p += 256) {   // 16 rows x 48 ch
    int r = p / 48, ch = p - r * 48;
    float s = 0.f;
#pragma unroll
    for (int k = 0; k < 9; ++k) s += wd[r][k] * xg[jn[r][k] * 52 + ch];
    tx[r * 48 + ch] = -din[r] * s;
  }
  __syncthreads();

  for (int p = tid; p < 768; p += 256) {   // 16 rows x 48 outs
    int r = p / 48, o = p - r * 48;
    float acc = bsh[o];
#pragma unroll
    for (int cc = 0; cc < 48; ++cc)
      acc += xr[r * 48 + cc] * w0s[cc * 48 + o] + tx[r * 48 + cc] * w1s[cc * 48 + o];
    out[(r0 + r) * 48 + o] = fmaxf(acc, 0.f);
  }
}

extern "C" void kernel_launch(void* const* d_in, const int* in_sizes, int n_in,
                              void* d_out, int out_size, void* d_ws, size_t ws_size,
                              hipStream_t stream) {
  const float* x  = (const float*)d_in[0];
  const float* W0 = (const float*)d_in[1];
  const float* W1 = (const float*)d_in[2];
  const float* b  = (const float*)d_in[3];
  float* out = (float*)d_out;
  char* ws = (char*)d_ws;
  float*          xg   = (float*)(ws);                       // 3,407,872 B
  unsigned short* xh   = (unsigned short*)(ws + 3407872);    // 2,097,152 B
  unsigned short* xl   = (unsigned short*)(ws + 5505024);    // 2,097,152 B
  float*          sqv  = (float*)(ws + 7602176);             //    65,536 B
  int*            nbr  = (int*)(ws + 7667712);               //   589,824 B
  int*            deg  = (int*)(ws + 8257536);               //    65,536 B

  prep_kernel<<<1024, 256, 0, stream>>>(x, xg, xh, xl, sqv, deg);
  knn_kernel<<<256, 512, 0, stream>>>(xh, xl, sqv, nbr, deg);
  out_kernel<<<1024, 256, 0, stream>>>(xg, nbr, deg, W0, W1, b, out);
}

// Round 15
// 171.387 us; speedup vs baseline: 1.0551x; 1.0551x over previous
//
#include <hip/hip_runtime.h>

#define NN 16384   // total nodes (4*64*64)
#define CC 48      // channels

typedef __attribute__((ext_vector_type(8))) short bf16x8;
typedef __attribute__((ext_vector_type(4))) float f32x4;

__device__ __forceinline__ unsigned short f2bf(float f) {
  unsigned u = __float_as_uint(f);
  unsigned r = ((u >> 16) & 1u) + 0x7fffu;   // RNE
  return (unsigned short)((u + r) >> 16);
}
__device__ __forceinline__ float bf2f(unsigned short h) {
  return __uint_as_float(((unsigned)h) << 16);
}

// Parallel sorted-insert of key c into ascending q[0..8] (verified R0 form).
// FROZEN: 8 datatype/gating variants lost to this form (R3-R5, R8). The ILP
// surface is also mapped: 4 chains/SIMD at max stream length is the optimum
// (R11: 2 chains 148->103us; R12: 4 chains @1 wave/SIMD = same; R14: 2
// waves/SIMD regressed to 114us on per-wave overhead). Structural floor:
// ~29us/SIMD unavoidable DP issue (1.05M wave-inserts x 17 f64-ops x 4cyc)
// + key-build + loop overhead ~= 50us issue, 103us wall.
__device__ __forceinline__ void ins9(double c, double q[9]) {
  double m1 = fmin(q[1], c), m2 = fmin(q[2], c), m3 = fmin(q[3], c),
         m4 = fmin(q[4], c), m5 = fmin(q[5], c), m6 = fmin(q[6], c),
         m7 = fmin(q[7], c), m8 = fmin(q[8], c);
  double n0 = fmin(q[0], c);
  double n1 = fmax(q[0], m1), n2 = fmax(q[1], m2), n3 = fmax(q[2], m3),
         n4 = fmax(q[3], m4), n5 = fmax(q[4], m5), n6 = fmax(q[5], m6),
         n7 = fmax(q[6], m7), n8 = fmax(q[7], m8);
  q[0] = n0; q[1] = n1; q[2] = n2; q[3] = n3; q[4] = n4;
  q[5] = n5; q[6] = n6; q[7] = n7; q[8] = n8;
}

// 9-way u64 sorted-merge insert used by the staging merges (verified form).
__device__ __forceinline__ void mrg9(const unsigned long long* ob,
                                     unsigned long long q9u[9]) {
  for (int k = 0; k < 9; ++k) {
    unsigned long long key = ob[k];
    if (key >= q9u[8]) break;          // source sorted ascending
    unsigned long long cu = key;
#pragma unroll
    for (int kk = 0; kk < 9; ++kk) {
      bool lt = cu < q9u[kk];
      unsigned long long mn = lt ? cu : q9u[kk];
      cu      = lt ? q9u[kk] : cu;
      q9u[kk] = mn;
    }
  }
}

// ---------- kernel 1: prep, 1024 blocks x 16-node slice (verified R10) ----------
__global__ __launch_bounds__(256) void prep_kernel(const float* __restrict__ x,
                                                   float* __restrict__ xg,
                                                   unsigned short* __restrict__ xh,
                                                   unsigned short* __restrict__ xl,
                                                   float* __restrict__ sqv,
                                                   int* __restrict__ deg) {
  __shared__ __align__(16) float tile[48][20];   // 16 cols + pad to 20 (80B rows)
  __shared__ float sqcol[16];
  int tid = threadIdx.x;
  int n0    = blockIdx.x * 16;          // first node of this slice
  int batch = n0 >> 12;
  int hw0   = n0 & 4095;                // 16-aligned within the image
  if (tid < 16) deg[n0 + tid] = 0;
  const float4* x4 = (const float4*)x;
  if (tid < 192) {                      // 48 rows x 4 float4 (16 cols)
    int r = tid >> 2, c4 = tid & 3;
    float4 v = x4[(batch * 48 + r) * 1024 + (hw0 >> 2) + c4];
    *(float4*)&tile[r][c4 * 4] = v;
  }
  __syncthreads();
  if (tid < 16) {
    float s = 0.f;
#pragma unroll
    for (int r = 0; r < 48; ++r) { float v = tile[r][tid]; s += v * v; }
    sqcol[tid] = s;
    int node = n0 + tid;
    sqv[node] = (node == NN - 1) ? __builtin_inff() : s;
  }
  __syncthreads();
  float4* xg4 = (float4*)xg;
  if (tid < 208) {                      // 16 nodes x 13 float4
    int col = tid / 13, q = tid - col * 13;
    float4 v;
    if (q < 12) {
      v.x = tile[q * 4 + 0][col]; v.y = tile[q * 4 + 1][col];
      v.z = tile[q * 4 + 2][col]; v.w = tile[q * 4 + 3][col];
    } else {
      v.x = sqcol[col]; v.y = 0.f; v.z = 0.f; v.w = 0.f;
    }
    xg4[(n0 + col) * 13 + q] = v;
  }
  {                                     // 16 nodes x 16 ch-quads = 256 threads
    int col = tid >> 4, cq = tid & 15, ch = cq * 4;
    ushort4 h4, l4;
    if (ch < 48) {
      float v0 = tile[ch + 0][col], v1 = tile[ch + 1][col],
            v2 = tile[ch + 2][col], v3 = tile[ch + 3][col];
      h4.x = f2bf(v0); h4.y = f2bf(v1); h4.z = f2bf(v2); h4.w = f2bf(v3);
      l4.x = f2bf(v0 - bf2f(h4.x)); l4.y = f2bf(v1 - bf2f(h4.y));
      l4.z = f2bf(v2 - bf2f(h4.z)); l4.w = f2bf(v3 - bf2f(h4.w));
    } else {
      h4.x = h4.y = h4.z = h4.w = 0;
      l4.x = l4.y = l4.z = l4.w = 0;
    }
    size_t o = (size_t)(n0 + col) * 64 + ch;
    *(ushort4*)(xh + o) = h4;
    *(ushort4*)(xl + o) = l4;
  }
}

// ---------- kernel 2: QUAD-QUERY MFMA distance + exact f64 top-9 (verified R12) ----------
// Best measured configuration: block = query tiles 4*bid..4*bid+3, 4 waves
// each stream the full batch quarter (64 tiles), 4 independent insert chains
// per wave (= 4 chains/SIMD at 1 block/CU). knn = 102.8us, VALUBusy 60%,
// VGPR 112, no spill. R13/R14 (2 waves/SIMD) regressed: halved streams
// doubled per-wave fixed overhead (+8-list merges) for less stall recovery.
__global__ __launch_bounds__(256, 2) void knn_kernel(const unsigned short* __restrict__ xh,
                                                     const unsigned short* __restrict__ xl,
                                                     const float* __restrict__ sqv,
                                                     int* __restrict__ nbr,
                                                     int* __restrict__ deg) {
  __shared__ unsigned long long fin[4][4][64][9];   // [query][wave][lane][k] 73.7KB
  int tid = threadIdx.x, wv = tid >> 6, lane = tid & 63;
  int qt0 = blockIdx.x * 4;
  int col = lane & 15, quad = lane >> 4;
  int batch = qt0 >> 8;
  int cbase = batch * 4096 + wv * 1024;   // this wave's candidate quarter

  // resident B-frags: 4 query tiles (static indexing via full unroll)
  bf16x8 bh0[4], bh1[4], bl0[4], bl1[4];
#pragma unroll
  for (int q = 0; q < 4; ++q) {
    int qn = (qt0 + q) * 16 + col;
    bh0[q] = *(const bf16x8*)(xh + (size_t)qn * 64 + quad * 8);
    bh1[q] = *(const bf16x8*)(xh + (size_t)qn * 64 + 32 + quad * 8);
    bl0[q] = *(const bf16x8*)(xl + (size_t)qn * 64 + quad * 8);
    bl1[q] = *(const bf16x8*)(xl + (size_t)qn * 64 + 32 + quad * 8);
  }

  double q9[4][9];
#pragma unroll
  for (int q = 0; q < 4; ++q)
#pragma unroll
    for (int k = 0; k < 9; ++k) q9[q][k] = __builtin_inf();

  // prefetch tile 0: shared A-frags (candidate node cbase + col) + sq float4
  const unsigned short* pah = xh + ((size_t)(cbase + col) * 64 + quad * 8);
  const unsigned short* pal = xl + ((size_t)(cbase + col) * 64 + quad * 8);
  const float*          psq = sqv + (cbase + quad * 4);
  bf16x8 nh0 = *(const bf16x8*)(pah);
  bf16x8 nh1 = *(const bf16x8*)(pah + 32);
  bf16x8 nl0 = *(const bf16x8*)(pal);
  bf16x8 nl1 = *(const bf16x8*)(pal + 32);
  float4 nsq = *(const float4*)(psq);

  double od = 0.0;   // ordinal base = t*4 (exact integer in f64), shared
  for (int t = 0; t < 64; ++t) {
    bf16x8 ch0 = nh0, ch1 = nh1, cl0 = nl0, cl1 = nl1;
    float4 csq = nsq;
    int adv = (t < 63) ? 1024 : 0;       // 16 nodes * 64 ch
    pah += adv; pal += adv;
    nh0 = *(const bf16x8*)(pah);
    nh1 = *(const bf16x8*)(pah + 32);
    nl0 = *(const bf16x8*)(pal);
    nl1 = *(const bf16x8*)(pal + 32);
    psq += (t < 63) ? 16 : 0;
    nsq = *(const float4*)(psq);

    f32x4 acc[4];
#pragma unroll
    for (int q = 0; q < 4; ++q) acc[q] = (f32x4){0.f, 0.f, 0.f, 0.f};
#pragma unroll
    for (int q = 0; q < 4; ++q)
      acc[q] = __builtin_amdgcn_mfma_f32_16x16x32_bf16(ch0, bh0[q], acc[q], 0, 0, 0);
#pragma unroll
    for (int q = 0; q < 4; ++q)
      acc[q] = __builtin_amdgcn_mfma_f32_16x16x32_bf16(ch1, bh1[q], acc[q], 0, 0, 0);
#pragma unroll
    for (int q = 0; q < 4; ++q)
      acc[q] = __builtin_amdgcn_mfma_f32_16x16x32_bf16(ch0, bl0[q], acc[q], 0, 0, 0);
#pragma unroll
    for (int q = 0; q < 4; ++q)
      acc[q] = __builtin_amdgcn_mfma_f32_16x16x32_bf16(ch1, bl1[q], acc[q], 0, 0, 0);
#pragma unroll
    for (int q = 0; q < 4; ++q)
      acc[q] = __builtin_amdgcn_mfma_f32_16x16x32_bf16(cl0, bh0[q], acc[q], 0, 0, 0);
#pragma unroll
    for (int q = 0; q < 4; ++q)
      acc[q] = __builtin_amdgcn_mfma_f32_16x16x32_bf16(cl1, bh1[q], acc[q], 0, 0, 0);

    float sq4[4] = {csq.x, csq.y, csq.z, csq.w};
#pragma unroll
    for (int reg = 0; reg < 4; ++reg) {
      double ob = od + (double)reg;
#pragma unroll
      for (int q = 0; q < 4; ++q) {       // 4 independent insert chains
        float d = fmaf(-2.f, acc[q][reg], sq4[reg]);
        unsigned k32 = __float_as_uint(d);
        k32 = ((int)k32 >= 0) ? (k32 | 0x80000000u) : ~k32;   // sortable map
        double key = fma((double)k32, 256.0, ob);   // exact 40-bit int
        ins9(key, q9[q]);
      }
    }
    od += 4.0;
  }

  // decode each queue -> packed u64 -> LDS (frees the f64 queue regs per q)
#pragma unroll
  for (int q = 0; q < 4; ++q) {
#pragma unroll
    for (int k = 0; k < 9; ++k) {
      double d  = q9[q][k];
      double hi = floor(d * 0.00390625);     // d * 2^-8, exact
      double lo = d - hi * 256.0;            // ordinal o, exact
      unsigned k32 = (unsigned)hi;
      int o = (int)lo;
      int j = cbase + (o >> 2) * 16 + quad * 4 + (o & 3);
      fin[q][wv][lane][k] = ((unsigned long long)k32 << 14) | (unsigned)j;
    }
  }
  __threadfence_block();
  if (lane < 16) {
    // stage 1: per query, merge this wave's 4 quads
#pragma unroll
    for (int q = 0; q < 4; ++q) {
      unsigned long long qu[9];
#pragma unroll
      for (int k = 0; k < 9; ++k) qu[k] = fin[q][wv][lane][k];
#pragma unroll
      for (int qd = 1; qd < 4; ++qd) mrg9(fin[q][wv][qd * 16 + lane], qu);
#pragma unroll
      for (int k = 0; k < 9; ++k) fin[q][wv][lane][k] = qu[k];
    }
  }
  __syncthreads();
  // stage 2: wave w finalizes query w (4-way parallel); write nbr/deg
  if (lane < 16) {
    unsigned long long qu[9];
#pragma unroll
    for (int k = 0; k < 9; ++k) qu[k] = fin[wv][wv][lane][k];
#pragma unroll
    for (int ow = 0; ow < 4; ++ow) {
      if (ow == wv) continue;
      mrg9(fin[wv][ow][lane], qu);
    }
    int i = (qt0 + wv) * 16 + lane;
    int outi[9];
#pragma unroll
    for (int k = 0; k < 9; ++k) outi[k] = (int)(qu[k] & 0x3FFFull);
    // node 16383 sits alone in "batch 4": neighbors {16383, 0..7}
    if (i == NN - 1) {
      outi[0] = NN - 1;
#pragma unroll
      for (int k = 1; k < 9; ++k) outi[k] = k - 1;
    }
#pragma unroll
    for (int k = 0; k < 9; ++k) {
      nbr[i * 9 + k] = outi[k];
      atomicAdd(&deg[outi[k]], 1);
    }
  }
}

// ---------- kernel 3: tx1 gather + out = relu(xf@W0 + tx1@W1 + b) ----------
// Verified R7/R10 version (1024 blocks x 16 rows). Unchanged.
__global__ __launch_bounds__(256) void out_kernel(const float* __restrict__ xg,
                                                  const int* __restrict__ nbr,
                                                  const int* __restrict__ deg,
                                                  const float* __restrict__ W0,
                                                  const float* __restrict__ W1,
                                                  const float* __restrict__ bias,
                                                  float* __restrict__ out) {
  __shared__ float w0s[48 * 48], w1s[48 * 48], bsh[48];
  __shared__ __align__(16) float xr[16 * 48];
  __shared__ float tx[16 * 48];
  __shared__ float wd[16][9];
  __shared__ int   jn[16][9];
  __shared__ float din[16];
  int tid = threadIdx.x;
  int r0  = blockIdx.x * 16;

  const float4* W04 = (const float4*)W0;
  const float4* W14 = (const float4*)W1;
  float4* w0s4 = (float4*)w0s;
  float4* w1s4 = (float4*)w1s;
  for (int p = tid; p < 576; p += 256) { w0s4[p] = W04[p]; w1s4[p] = W14[p]; }
  if (tid < 48) bsh[tid] = bias[tid];
  if (tid < 16) {
    int d = deg[r0 + tid];
    din[tid] = d > 0 ? rsqrtf((float)d) : 0.0f;
  }
  const float4* xg4 = (const float4*)xg;
  float4* xr4 = (float4*)xr;
  if (tid < 192) {                      // 16 rows x 12 float4
    int r = tid / 12, q = tid - r * 12;
    xr4[r * 12 + q] = xg4[(r0 + r) * 13 + q];
  }
  if (tid < 144) {                      // 16 rows x 9 neighbors
    int r = tid / 9, k = tid - r * 9;
    int j = nbr[(r0 + r) * 9 + k];
    jn[r][k] = j;
    int d = deg[j];
    wd[r][k] = d > 0 ? rsqrtf((float)d) : 0.0f;
  }
  __syncthreads();

  for (int p = tid; p < 768; p += 256) {   // 16 rows x 48 ch
    int r = p / 48, ch = p - r * 48;
    float s = 0.f;
#pragma unroll
    for (int k = 0; k < 9; ++k) s += wd[r][k] * xg[jn[r][k] * 52 + ch];
    tx[r * 48 + ch] = -din[r] * s;
  }
  __syncthreads();

  for (int p = tid; p < 768; p += 256) {   // 16 rows x 48 outs
    int r = p / 48, o = p - r * 48;
    float acc = bsh[o];
#pragma unroll
    for (int cc = 0; cc < 48; ++cc)
      acc += xr[r * 48 + cc] * w0s[cc * 48 + o] + tx[r * 48 + cc] * w1s[cc * 48 + o];
    out[(r0 + r) * 48 + o] = fmaxf(acc, 0.f);
  }
}

extern "C" void kernel_launch(void* const* d_in, const int* in_sizes, int n_in,
                              void* d_out, int out_size, void* d_ws, size_t ws_size,
                              hipStream_t stream) {
  const float* x  = (const float*)d_in[0];
  const float* W0 = (const float*)d_in[1];
  const float* W1 = (const float*)d_in[2];
  const float* b  = (const float*)d_in[3];
  float* out = (float*)d_out;
  char* ws = (char*)d_ws;
  float*          xg   = (float*)(ws);                       // 3,407,872 B
  unsigned short* xh   = (unsigned short*)(ws + 3407872);    // 2,097,152 B
  unsigned short* xl   = (unsigned short*)(ws + 5505024);    // 2,097,152 B
  float*          sqv  = (float*)(ws + 7602176);             //    65,536 B
  int*            nbr  = (int*)(ws + 7667712);               //   589,824 B
  int*            deg  = (int*)(ws + 8257536);               //    65,536 B

  prep_kernel<<<1024, 256, 0, stream>>>(x, xg, xh, xl, sqv, deg);
  knn_kernel<<<256, 256, 0, stream>>>(xh, xl, sqv, nbr, deg);
  out_kernel<<<1024, 256, 0, stream>>>(xg, nbr, deg, W0, W1, b, out);
}